// Round 1
// 400.129 us; speedup vs baseline: 1.2691x; 1.2691x over previous
//
#include <hip/hip_runtime.h>

typedef unsigned int u32;
typedef unsigned short u16;
typedef float f32x4 __attribute__((ext_vector_type(4)));
typedef short s16x8 __attribute__((ext_vector_type(8)));

constexpr float SCALE = 0.17677669529663687f;  // 32^-0.5

__device__ __forceinline__ u16 f2b(float f) {
  u32 x = __float_as_uint(f);
  return (u16)((x + 0x7fffu + ((x >> 16) & 1u)) >> 16);  // RNE-ish
}
__device__ __forceinline__ float b2f(u16 s) { return __uint_as_float(((u32)s) << 16); }
__device__ __forceinline__ u32 pk2(float lo, float hi) {
  return (u32)f2b(lo) | ((u32)f2b(hi) << 16);
}

union FU8 { s16x8 v; u32 u[4]; uint4 q; };

// Barrier WITHOUT the vmcnt(0) drain __syncthreads() would emit: LDS writes
// must be visible (lgkmcnt), but prefetched global loads stay in flight.
__device__ __forceinline__ void barrier_lds() {
  asm volatile("s_waitcnt lgkmcnt(0)" ::: "memory");
  __builtin_amdgcn_s_barrier();
}

// ws tables (u16 bf16):
//   TK  [h][240][32] at 0      (k_embed, rows>=225 zero)   for QE = Q x TK^T
//   TQ  [h][240][32] at 30720  (q_embed*SCALE)             for KR = K x TQ^T
//   TVt [h][32][256] at 61440  (v_embed^T, pp>=225 zero)   for Aacc x VE
__global__ __launch_bounds__(256) void prep_tabs(const float* __restrict__ rpe,
                                                 u16* __restrict__ tabs) {
  int id = blockIdx.x * 256 + threadIdx.x;
  if (id >= 94208) return;
  float val = 0.f;
  if (id < 61440) {
    int tbl = id / 30720;          // 0 = TK, 1 = TQ
    int r   = id % 30720;
    int h   = r / 7680;
    int rr  = r % 7680;
    int row = rr / 32, c = rr % 32;
    if (row < 225) {
      val = rpe[row * 384 + h * 96 + (tbl == 0 ? 32 : 0) + c];
      if (tbl == 1) val *= SCALE;
    }
  } else {
    int id2 = id - 61440;
    int h  = id2 / 8192;
    int r2 = id2 % 8192;
    int pp = r2 % 256;
    int c  = r2 / 256;
    if (pp < 225) val = rpe[pp * 384 + h * 96 + 64 + c];
  }
  tabs[id] = f2b(val);
}

// 4 waves per (window, head); wave W owns i-strips {2W, 2W+1}.
// LDS pool (u16 units), 25600 u16 = 51200 B -> 3 blocks/CU:
//   vt   [32][136]      @0      P0->P2   (V^T staging)
//   qec  [128][64] swz  @4352   P1->P2   (gathered q.k_embed, u32 pairs)
//   p2b  [128][64] swz  @12544  P2->P4   (attn pair-sums, u32 pairs)
//   krt  2x[16][152]    @20736  P2       (KRT strip, double-buffered)
//   scW  4x[16][152]    @12544  P1       (per-wave QE strips, over p2b+krt)
//   opv  [32][129]      @0      P3+      (normalized O_pv, over dead vt)
//   aacc 4x[16][168]    P4: W<3 @4352+W*2688 (over dead qec), W3 @20736 (over krt)
__global__ __launch_bounds__(256, 3) void swin_mfma(
    const float* __restrict__ qkv,   // [4,128,128,2,384]
    const u16*   __restrict__ tabs,
    float* __restrict__ out) {       // [4,128,128,2,128]
  __shared__ __align__(16) u16 pool[25600];
  u16* const vt  = pool;
  u16* const qec = pool + 4352;
  u16* const p2b = pool + 12544;
  u16* const krt = pool + 20736;
  u32* const qec32 = (u32*)qec;
  u32* const p2b32 = (u32*)p2b;

  const int t = threadIdx.x;
  const int W = t >> 6;
  const int t64 = t & 63;
  const int li = t64 & 15, quad = t64 >> 4;
  u16* const scW = pool + 12544 + W * 2432;
  u16* const opv = pool;
  u16* const aaccW = (W < 3) ? (pool + 4352 + W * 2688) : (pool + 20736);

  int blk = blockIdx.x;
  blk = ((blk & 7) << 9) | (blk >> 3);   // XCD-aware swizzle (4096 % 8 == 0)
  const int h = blk & 3;
  const int w = blk >> 2;
  const int b = w >> 8;
  const int nw = w & 255;
  const int wi = nw >> 4, wj = nw & 15;
  const bool wi15 = (wi == 15), wj15 = (wj == 15);
  const int swl = (li & 7) << 3;   // XOR swizzle key (row & 7) << 3

  auto tokoff = [&](int m) -> int {
    int y = (wi * 8 + (m >> 4) + 4) & 127;
    int x = (wj * 8 + ((m >> 1) & 7) + 4) & 127;
    return (((b * 128 + y) * 128 + x) * 2 + (m & 1)) * 384;
  };

  // ---- Phase 0: V^T staging + Q fragments + ALL K fragments preloaded ----
  {
    int tok = t >> 1, chb = (t & 1) * 16;
    int vb = tokoff(tok) + 256 + h * 32 + chb;
    #pragma unroll
    for (int g = 0; g < 4; ++g) {
      float4 v4 = *(const float4*)(qkv + vb + g * 4);
      vt[(chb + g * 4 + 0) * 136 + tok] = f2b(v4.x);
      vt[(chb + g * 4 + 1) * 136 + tok] = f2b(v4.y);
      vt[(chb + g * 4 + 2) * 136 + tok] = f2b(v4.z);
      vt[(chb + g * 4 + 3) * 136 + tok] = f2b(v4.w);
    }
  }
  FU8 qf[2];
  #pragma unroll
  for (int g = 0; g < 2; ++g) {
    int base = tokoff((2 * W + g) * 16 + li) + h * 32 + quad * 8;
    float4 a = *(const float4*)(qkv + base);
    float4 c = *(const float4*)(qkv + base + 4);
    qf[g].u[0] = pk2(a.x * SCALE, a.y * SCALE);
    qf[g].u[1] = pk2(a.z * SCALE, a.w * SCALE);
    qf[g].u[2] = pk2(c.x * SCALE, c.y * SCALE);
    qf[g].u[3] = pk2(c.z * SCALE, c.w * SCALE);
  }
  FU8 kf[8];
  #pragma unroll
  for (int js = 0; js < 8; ++js) {
    int kb = tokoff(js * 16 + li) + 128 + h * 32 + quad * 8;
    float4 a = *(const float4*)(qkv + kb);
    float4 c = *(const float4*)(qkv + kb + 4);
    kf[js].u[0] = pk2(a.x, a.y); kf[js].u[1] = pk2(a.z, a.w);
    kf[js].u[2] = pk2(c.x, c.y); kf[js].u[3] = pk2(c.z, c.w);
  }

  const f32x4 zf = {0.f, 0.f, 0.f, 0.f};

  // ---- Phase 1: QE strips + gather into qec (all per-wave: NO barriers) ----
  #pragma unroll
  for (int g = 0; g < 2; ++g) {
    int ss = 2 * W + g;
    int t0 = (15 * ss) >> 4;
    #pragma unroll
    for (int tt = 0; tt < 9; ++tt) {
      int pt = t0 + tt;
      FU8 bf;
      bf.q = *(const uint4*)(tabs + h * 7680 + (pt * 16 + li) * 32 + quad * 8);
      f32x4 acc = __builtin_amdgcn_mfma_f32_16x16x32_bf16(qf[g].v, bf.v, zf, 0, 0, 0);
      int rb = (quad * 4) * 152 + tt * 16 + li;        // compact col = p - t0*16
      scW[rb] = f2b(acc[0]); scW[rb + 152] = f2b(acc[1]);
      scW[rb + 304] = f2b(acc[2]); scW[rb + 456] = f2b(acc[3]);
    }
    int pbase = (ss + 7) * 15 + (li >> 1) + 7;
    int co = t0 * 16;
    int row = ss * 16 + li;
    #pragma unroll
    for (int g2 = 0; g2 < 8; ++g2) {
      int j64 = quad * 16 + 2 * g2;
      int p0 = pbase - 15 * (j64 >> 3) - (j64 & 7);
      int p1 = pbase - 15 * ((j64 + 1) >> 3) - ((j64 + 1) & 7);
      u32 lo = scW[li * 152 + (p0 - co)];
      u32 hi = scW[li * 152 + (p1 - co)];
      qec32[row * 32 + ((j64 ^ swl) >> 1)] = lo | (hi << 16);
    }
  }

  // prefetch KRT tables for js=0
  FU8 bfA, bfB, bfC;
  bfC.q = make_uint4(0, 0, 0, 0);
  {
    const int t0k = (7 * 15) >> 4;
    const u16* tq = tabs + 30720 + h * 7680;
    bfA.q = *(const uint4*)(tq + ((t0k + W) * 16 + li) * 32 + quad * 8);
    bfB.q = *(const uint4*)(tq + ((t0k + W + 4) * 16 + li) * 32 + quad * 8);
    if (W == 0) bfC.q = *(const uint4*)(tq + ((t0k + 8) * 16 + li) * 32 + quad * 8);
  }

  barrier_lds();   // P0/P1 -> flash

  // ---- Phase 2: flash over j-strips (ONE barrier per strip) ----
  f32x4 ot[2][2] = {{zf, zf}, {zf, zf}};
  float lsum[2] = {0.f, 0.f};
  const int rx_i = wj15 ? (((li >> 1) < 4) ? 1 : 2) : 0;
  u32 ppk[2][2] = {{0, 0}, {0, 0}};

  #pragma unroll
  for (int js = 0; js < 8; ++js) {
    const int cok = (((7 - js) * 15) >> 4) * 16;
    u16* const kbuf = krt + (js & 1) * 2432;   // double-buffered
    {
      f32x4 acc = __builtin_amdgcn_mfma_f32_16x16x32_bf16(kf[js].v, bfA.v, zf, 0, 0, 0);
      int rb = (quad * 4) * 152 + W * 16 + li;
      kbuf[rb] = f2b(acc[0]); kbuf[rb + 152] = f2b(acc[1]);
      kbuf[rb + 304] = f2b(acc[2]); kbuf[rb + 456] = f2b(acc[3]);
      acc = __builtin_amdgcn_mfma_f32_16x16x32_bf16(kf[js].v, bfB.v, zf, 0, 0, 0);
      rb = (quad * 4) * 152 + (W + 4) * 16 + li;
      kbuf[rb] = f2b(acc[0]); kbuf[rb + 152] = f2b(acc[1]);
      kbuf[rb + 304] = f2b(acc[2]); kbuf[rb + 456] = f2b(acc[3]);
      if (W == (js & 3)) {                      // rotating owner of tile 8
        acc = __builtin_amdgcn_mfma_f32_16x16x32_bf16(kf[js].v, bfC.v, zf, 0, 0, 0);
        rb = (quad * 4) * 152 + 128 + li;
        kbuf[rb] = f2b(acc[0]); kbuf[rb + 152] = f2b(acc[1]);
        kbuf[rb + 304] = f2b(acc[2]); kbuf[rb + 456] = f2b(acc[3]);
      }
    }
    if (js < 7) {   // prefetch next strip's tables: stays in flight across barrier
      const int t0n = ((7 - (js + 1)) * 15) >> 4;
      const u16* tq = tabs + 30720 + h * 7680;
      bfA.q = *(const uint4*)(tq + ((t0n + W) * 16 + li) * 32 + quad * 8);
      bfB.q = *(const uint4*)(tq + ((t0n + W + 4) * 16 + li) * 32 + quad * 8);
      if (W == ((js + 1) & 3))
        bfC.q = *(const uint4*)(tq + ((t0n + 8) * 16 + li) * 32 + quad * 8);
    }
    barrier_lds();

    __builtin_amdgcn_s_setprio(1);
    const int ry_j = wi15 ? ((js < 4) ? 1 : 2) : 0;
    u32 cpk[2][2];
    #pragma unroll
    for (int g = 0; g < 2; ++g) {
      const int it = 2 * W + g;
      f32x4 s = __builtin_amdgcn_mfma_f32_16x16x32_bf16(kf[js].v, qf[g].v, zf, 0, 0, 0);
      const int ry_i = wi15 ? ((it < 4) ? 1 : 2) : 0;
      const int i = it * 16 + li;
      const int pbq = (it + 7) * 15 + (li >> 1) + 7 - 15 * js;
      u32 qe2 = qec32[i * 32 + (((js * 8 + 2 * quad) ^ swl) >> 1)];
      float qeL = b2f((u16)qe2), qeH = b2f((u16)(qe2 >> 16));
      float e[4];
      #pragma unroll
      for (int reg = 0; reg < 4; ++reg) {
        int jl = quad * 4 + reg;
        int jw = jl >> 1;
        int rx_j = wj15 ? ((jw < 4) ? 1 : 2) : 0;
        float v = s[reg] + b2f(kbuf[jl * 152 + (pbq - jw - cok)]) +
                  ((reg < 2) ? qeL : qeH);
        bool open = (ry_i == ry_j) && (rx_i == rx_j) &&
                    !((it == js) && ((li >> 1) == jw) && (li != jl));
        e[reg] = open ? __expf(v) : 0.f;
      }
      float cs = e[0] + e[1] + e[2] + e[3];
      cs += __shfl_xor(cs, 16, 64);
      cs += __shfl_xor(cs, 32, 64);
      lsum[g] += cs;
      p2b32[i * 32 + (((js * 8 + 2 * quad) ^ swl) >> 1)] = pk2(e[0] + e[1], e[2] + e[3]);
      cpk[g][0] = pk2(e[0], e[1]);
      cpk[g][1] = pk2(e[2], e[3]);
    }

    if (js & 1) {  // PV for the completed 32-j block: P via shuffles, no LDS
      const int pairbase = (js >> 1) * 32;
      FU8 vf0, vf1;
      vf0.q = *(const uint4*)&vt[li * 136 + pairbase + quad * 8];
      vf1.q = *(const uint4*)&vt[(16 + li) * 136 + pairbase + quad * 8];
      #pragma unroll
      for (int g = 0; g < 2; ++g) {
        FU8 pf;   // B-frag: k = quad*8+e -> src quad (2*(quad&1)+(w>>1)), word (w&1)
        #pragma unroll
        for (int w2 = 0; w2 < 4; ++w2) {
          int srcLane = (2 * (quad & 1) + (w2 >> 1)) * 16 + li;
          u32 rp = (u32)__shfl((int)ppk[g][w2 & 1], srcLane, 64);
          u32 rc = (u32)__shfl((int)cpk[g][w2 & 1], srcLane, 64);
          pf.u[w2] = (quad < 2) ? rp : rc;
        }
        ot[0][g] = __builtin_amdgcn_mfma_f32_16x16x32_bf16(vf0.v, pf.v, ot[0][g], 0, 0, 0);
        ot[1][g] = __builtin_amdgcn_mfma_f32_16x16x32_bf16(vf1.v, pf.v, ot[1][g], 0, 0, 0);
      }
    } else {
      ppk[0][0] = cpk[0][0]; ppk[0][1] = cpk[0][1];
      ppk[1][0] = cpk[1][0]; ppk[1][1] = cpk[1][1];
    }
    __builtin_amdgcn_s_setprio(0);
  }

  barrier_lds();   // flash -> epilogue (vt/qec/krt now dead; all epilogue
                   // buffers are per-wave or same-wave -> no further barriers)

  // ---- Phase 3: normalize O_pv into opv ----
  float iv[2] = {1.f / lsum[0], 1.f / lsum[1]};
  #pragma unroll
  for (int ct = 0; ct < 2; ++ct)
    #pragma unroll
    for (int g = 0; g < 2; ++g) {
      int i = (2 * W + g) * 16 + li;
      #pragma unroll
      for (int reg = 0; reg < 4; ++reg)
        opv[(ct * 16 + quad * 4 + reg) * 129 + i] = f2b(ot[ct][g][reg] * iv[g]);
    }

  // ---- Phase 4: x_embed = Aacc x VE per own strip (compact 160-col window) ----
  #pragma unroll
  for (int g = 0; g < 2; ++g) {
    int ss = 2 * W + g;
    int t0 = (15 * ss) >> 4;
    int kb0 = (t0 & ~1) * 16;     // 32-aligned window base
    #pragma unroll
    for (int k = 0; k < 6; ++k) {
      int idx = k * 64 + t64;
      if (idx < 336) ((uint4*)aaccW)[idx] = make_uint4(0, 0, 0, 0);
    }
    int i = ss * 16 + li;
    int pbase = (ss + 7) * 15 + (li >> 1) + 7;
    #pragma unroll
    for (int g2 = 0; g2 < 8; ++g2) {
      int j64 = quad * 16 + 2 * g2;
      u32 ps = p2b32[i * 32 + ((j64 ^ swl) >> 1)];
      int p0 = pbase - 15 * (j64 >> 3) - (j64 & 7);
      int p1 = pbase - 15 * ((j64 + 1) >> 3) - ((j64 + 1) & 7);
      aaccW[li * 168 + (p0 - kb0)] = (u16)ps;
      aaccW[li * 168 + (p1 - kb0)] = (u16)(ps >> 16);
    }
    f32x4 xa0 = zf, xa1 = zf;
    #pragma unroll
    for (int kt = 0; kt < 5; ++kt) {
      FU8 af, bf0, bf1;
      af.q = *(const uint4*)&aaccW[li * 168 + kt * 32 + quad * 8];
      bf0.q = *(const uint4*)(tabs + 61440 + h * 8192 + li * 256 + kb0 + kt * 32 + quad * 8);
      bf1.q = *(const uint4*)(tabs + 61440 + h * 8192 + (16 + li) * 256 + kb0 + kt * 32 + quad * 8);
      xa0 = __builtin_amdgcn_mfma_f32_16x16x32_bf16(af.v, bf0.v, xa0, 0, 0, 0);
      xa1 = __builtin_amdgcn_mfma_f32_16x16x32_bf16(af.v, bf1.v, xa1, 0, 0, 0);
    }
    #pragma unroll
    for (int reg = 0; reg < 4; ++reg) {
      int irow = ss * 16 + quad * 4 + reg;
      float ivr = __shfl(iv[g], quad * 4 + reg, 64);
      int y = (wi * 8 + (irow >> 4) + 4) & 127;
      int x = (wj * 8 + ((irow >> 1) & 7) + 4) & 127;
      int ob = (((b * 128 + y) * 128 + x) * 2 + (irow & 1)) * 128 + h * 32;
      out[ob + li] = b2f(opv[li * 129 + irow]) + xa0[reg] * ivr;
      out[ob + 16 + li] = b2f(opv[(16 + li) * 129 + irow]) + xa1[reg] * ivr;
    }
  }
}

extern "C" void kernel_launch(void* const* d_in, const int* in_sizes, int n_in,
                              void* d_out, int out_size, void* d_ws, size_t ws_size,
                              hipStream_t stream) {
  const float* qkv = (const float*)d_in[0];
  // d_in[1] (attn_mask) and d_in[3] (rel_pos_index) unused: computed analytically.
  const float* rpe = (const float*)d_in[2];
  u16* tabs = (u16*)d_ws;  // 94208 u16 = 188,416 B

  prep_tabs<<<368, 256, 0, stream>>>(rpe, tabs);
  swin_mfma<<<4096, 256, 0, stream>>>(qkv, tabs, (float*)d_out);
}